// Round 7
// baseline (740.242 us; speedup 1.0000x reference)
//
#include <hip/hip_runtime.h>
#include <hip/hip_bf16.h>

#define N_NODES 100000
#define IN_F 128
#define OUT_F 64
#define BROWS 64                  // rows per bucket
#define NB 1563                   // ceil(100000/64)
#define BIN_TILE 2048             // edges per bin tile (8 per thread)

// ===========================================================================
// Kernel 1: support = input @ W    [N,128] x [128,64] -> [N,64]
// lane = row, A in LDS [64][129], wave-uniform W loads (scalar path)
// ===========================================================================
__global__ __launch_bounds__(256) void gemm_kernel(
    const float* __restrict__ in, const float* __restrict__ W,
    float* __restrict__ support)
{
    __shared__ float Alds[64 * 129];
    const int t = threadIdx.x;
    const long row0 = (long)blockIdx.x * 64;

    #pragma unroll
    for (int i = 0; i < 8; ++i) {
        int fi = t + i * 256;
        int r  = fi >> 5;
        int k4 = (fi & 31) << 2;
        float4 v = make_float4(0.f, 0.f, 0.f, 0.f);
        if (row0 + r < N_NODES)
            v = *(const float4*)(in + (row0 + r) * IN_F + k4);
        Alds[r * 129 + k4 + 0] = v.x;
        Alds[r * 129 + k4 + 1] = v.y;
        Alds[r * 129 + k4 + 2] = v.z;
        Alds[r * 129 + k4 + 3] = v.w;
    }
    __syncthreads();

    const int lane = t & 63;
    const int c0   = __builtin_amdgcn_readfirstlane((t >> 6) << 4);
    const float* __restrict__ Wp = W + c0;

    float acc[16];
    #pragma unroll
    for (int i = 0; i < 16; ++i) acc[i] = 0.f;

    const float* Ar = Alds + lane * 129;
    for (int k = 0; k < IN_F; ++k) {
        const float a = Ar[k];
        const float4 w0 = *(const float4*)(Wp + k * OUT_F + 0);
        const float4 w1 = *(const float4*)(Wp + k * OUT_F + 4);
        const float4 w2 = *(const float4*)(Wp + k * OUT_F + 8);
        const float4 w3 = *(const float4*)(Wp + k * OUT_F + 12);
        acc[0]  = fmaf(a, w0.x, acc[0]);  acc[1]  = fmaf(a, w0.y, acc[1]);
        acc[2]  = fmaf(a, w0.z, acc[2]);  acc[3]  = fmaf(a, w0.w, acc[3]);
        acc[4]  = fmaf(a, w1.x, acc[4]);  acc[5]  = fmaf(a, w1.y, acc[5]);
        acc[6]  = fmaf(a, w1.z, acc[6]);  acc[7]  = fmaf(a, w1.w, acc[7]);
        acc[8]  = fmaf(a, w2.x, acc[8]);  acc[9]  = fmaf(a, w2.y, acc[9]);
        acc[10] = fmaf(a, w2.z, acc[10]); acc[11] = fmaf(a, w2.w, acc[11]);
        acc[12] = fmaf(a, w3.x, acc[12]); acc[13] = fmaf(a, w3.y, acc[13]);
        acc[14] = fmaf(a, w3.z, acc[14]); acc[15] = fmaf(a, w3.w, acc[15]);
    }

    const long orow = row0 + lane;
    if (orow < N_NODES) {
        float* o = support + orow * OUT_F + c0;
        *(float4*)(o + 0)  = make_float4(acc[0],  acc[1],  acc[2],  acc[3]);
        *(float4*)(o + 4)  = make_float4(acc[4],  acc[5],  acc[6],  acc[7]);
        *(float4*)(o + 8)  = make_float4(acc[8],  acc[9],  acc[10], acc[11]);
        *(float4*)(o + 12) = make_float4(acc[12], acc[13], acc[14], acc[15]);
    }
}

// ===========================================================================
__global__ __launch_bounds__(256) void zero_kernel(int* __restrict__ p, int n)
{
    int i = blockIdx.x * 256 + threadIdx.x;
    if (i < n) p[i] = 0;
}

// ===========================================================================
// B1: per-bucket edge counts (LDS-aggregated histogram -> global add)
// ===========================================================================
__global__ __launch_bounds__(256) void count_kernel(
    const int* __restrict__ rows, int* __restrict__ cnt, int nE)
{
    __shared__ int hist[NB];
    const int t = threadIdx.x;
    for (int i = t; i < NB; i += 256) hist[i] = 0;
    __syncthreads();

    for (int e = blockIdx.x * 256 + t; e < nE; e += gridDim.x * 256)
        atomicAdd(&hist[rows[e] >> 6], 1);
    __syncthreads();

    for (int i = t; i < NB; i += 256) {
        int h = hist[i];
        if (h) atomicAdd(&cnt[i], h);
    }
}

// ===========================================================================
// B2: exclusive scan of NB counts (single block, 8 elems/thread).
// ===========================================================================
__global__ __launch_bounds__(256) void scan_kernel(
    const int* __restrict__ cnt, int* __restrict__ base,
    int* __restrict__ cursor, int nE)
{
    __shared__ int lds[256];
    const int t = threadIdx.x;
    const int i0 = t * 8;
    int c[8];
    int tot = 0;
    #pragma unroll
    for (int k = 0; k < 8; ++k) {
        c[k] = (i0 + k < NB) ? cnt[i0 + k] : 0;
        tot += c[k];
    }

    lds[t] = tot;
    __syncthreads();
    int sum = tot;
    #pragma unroll
    for (int off = 1; off < 256; off <<= 1) {
        int y = (t >= off) ? lds[t - off] : 0;
        __syncthreads();
        sum += y;
        lds[t] = sum;
        __syncthreads();
    }
    int run = sum - tot;

    #pragma unroll
    for (int k = 0; k < 8; ++k) {
        if (i0 + k < NB) { base[i0 + k] = run; cursor[i0 + k] = run; }
        run += c[k];
    }
    if (t == 0) base[NB] = nE;
}

// ===========================================================================
// B3: bin edges into bucket-grouped array (LDS hist -> rank; clustered writes)
// payload: x = (row&63)<<17 | col (col < 2^17), y = bits of val.
// ===========================================================================
__global__ __launch_bounds__(256) void bin_kernel(
    const int* __restrict__ rows, const int* __restrict__ cols,
    const float* __restrict__ vals, int* __restrict__ cursor,
    uint2* __restrict__ binned, int nE)
{
    __shared__ int hist[NB];
    __shared__ int lbase[NB];
    const int t  = threadIdx.x;
    const int tb = blockIdx.x * BIN_TILE;

    for (int i = t; i < NB; i += 256) hist[i] = 0;
    __syncthreads();

    int myr[8], myrank[8];
    #pragma unroll
    for (int i = 0; i < 8; ++i) {
        int e = tb + i * 256 + t;
        if (e < nE) {
            int r = rows[e];
            myr[i] = r;
            myrank[i] = atomicAdd(&hist[r >> 6], 1);
        } else myr[i] = -1;
    }
    __syncthreads();

    for (int i = t; i < NB; i += 256) {
        int h = hist[i];
        lbase[i] = h ? atomicAdd(&cursor[i], h) : 0;
    }
    __syncthreads();

    #pragma unroll
    for (int i = 0; i < 8; ++i) {
        int e = tb + i * 256 + t;
        if (e < nE) {
            int r = myr[i];
            unsigned pack = ((unsigned)(r & (BROWS - 1)) << 17) | (unsigned)cols[e];
            binned[lbase[r >> 6] + myrank[i]] =
                make_uint2(pack, __float_as_uint(vals[e]));
        }
    }
}

// ===========================================================================
// B4: per-bucket accumulate, asm-pinned MLP.
// 256 thr (4 waves)/block, one block per bucket, acc[64][64] = 16 KB LDS.
// Per wave: stage 64 edges' metadata in LDS (coalesced, wave-private), then
// process in 8 groups of 8 with a 2-bank register pipeline:
//   - loads are volatile inline-asm global_load_dword (fixed issue order,
//     cannot be sunk by the scheduler -- rounds 4-6 failure mode)
//   - each group's consumers are data-dependent on an asm s_waitcnt vmcnt(8)
//     that takes the 8 destination regs as "+v" operands (no hoisting)
// -> 8-16 wave-loads in flight per wave, ~300 per CU: latency covered.
// Metadata broadcast via uniform LDS reads + readfirstlane -> SGPRs.
// ===========================================================================
#define ISSUE1(G, CX, J) do {                                               \
    CX = __builtin_amdgcn_readfirstlane((int)mw[(J) * 2]);                  \
    const float* ap_ = supL + ((size_t)(((unsigned)CX) & 131071u) << 6);    \
    asm volatile("global_load_dword %0, %1, off" : "=v"(G) : "v"(ap_));    \
} while (0)

#define CONS1(G, CX, J) do {                                                \
    float vv_ = __uint_as_float(                                            \
        (unsigned)__builtin_amdgcn_readfirstlane((int)mw[(J) * 2 + 1]));    \
    atomicAdd(&acc[((((unsigned)CX) >> 17) << 6) + lane], vv_ * G);         \
} while (0)

#define ISSUE8(Bk, J0) do {                                                 \
    ISSUE1(g##Bk##0, cx##Bk##0, (J0) + 0);                                  \
    ISSUE1(g##Bk##1, cx##Bk##1, (J0) + 1);                                  \
    ISSUE1(g##Bk##2, cx##Bk##2, (J0) + 2);                                  \
    ISSUE1(g##Bk##3, cx##Bk##3, (J0) + 3);                                  \
    ISSUE1(g##Bk##4, cx##Bk##4, (J0) + 4);                                  \
    ISSUE1(g##Bk##5, cx##Bk##5, (J0) + 5);                                  \
    ISSUE1(g##Bk##6, cx##Bk##6, (J0) + 6);                                  \
    ISSUE1(g##Bk##7, cx##Bk##7, (J0) + 7);                                  \
} while (0)

#define CONS8(Bk, J0) do {                                                  \
    CONS1(g##Bk##0, cx##Bk##0, (J0) + 0);                                   \
    CONS1(g##Bk##1, cx##Bk##1, (J0) + 1);                                   \
    CONS1(g##Bk##2, cx##Bk##2, (J0) + 2);                                   \
    CONS1(g##Bk##3, cx##Bk##3, (J0) + 3);                                   \
    CONS1(g##Bk##4, cx##Bk##4, (J0) + 4);                                   \
    CONS1(g##Bk##5, cx##Bk##5, (J0) + 5);                                   \
    CONS1(g##Bk##6, cx##Bk##6, (J0) + 6);                                   \
    CONS1(g##Bk##7, cx##Bk##7, (J0) + 7);                                   \
} while (0)

#define WAITBANK(Bk, N) asm volatile("s_waitcnt vmcnt(" #N ")"              \
    : "+v"(g##Bk##0), "+v"(g##Bk##1), "+v"(g##Bk##2), "+v"(g##Bk##3),       \
      "+v"(g##Bk##4), "+v"(g##Bk##5), "+v"(g##Bk##6), "+v"(g##Bk##7))

__global__ __launch_bounds__(256, 6) void bucket_spmm(
    const int* __restrict__ base, const uint2* __restrict__ binned,
    const float* __restrict__ support, const float* __restrict__ bias,
    float* __restrict__ out)
{
    __shared__ float acc[BROWS * OUT_F];     // 16 KB
    __shared__ unsigned meta[4 * 128];       // 2 KB: 4 waves x 64 edges x uint2
    const int t = threadIdx.x;
    float4* acc4 = (float4*)acc;
    #pragma unroll
    for (int i = 0; i < 4; ++i)
        acc4[t + i * 256] = make_float4(0.f, 0.f, 0.f, 0.f);
    __syncthreads();

    const int b = blockIdx.x;
    const int s = base[b];
    const int e = base[b + 1];
    const int wid  = t >> 6;
    const int lane = t & 63;
    const float* supL = support + lane;
    unsigned* mw = &meta[wid * 128];         // wave-private 64-edge buffer

    for (int c0 = s + wid * 64; c0 < e; c0 += 256) {
        const int idx = c0 + lane;
        uint2 p = (idx < e) ? binned[idx] : make_uint2(0u, 0u);
        *(uint2*)&mw[lane * 2] = p;          // wave-sync: lgkmcnt ordering

        float gA0, gA1, gA2, gA3, gA4, gA5, gA6, gA7;
        float gB0, gB1, gB2, gB3, gB4, gB5, gB6, gB7;
        int cxA0, cxA1, cxA2, cxA3, cxA4, cxA5, cxA6, cxA7;
        int cxB0, cxB1, cxB2, cxB3, cxB4, cxB5, cxB6, cxB7;

        ISSUE8(A, 0);
        ISSUE8(B, 8);
        WAITBANK(A, 8);  CONS8(A, 0);
        ISSUE8(A, 16);
        WAITBANK(B, 8);  CONS8(B, 8);
        ISSUE8(B, 24);
        WAITBANK(A, 8);  CONS8(A, 16);
        ISSUE8(A, 32);
        WAITBANK(B, 8);  CONS8(B, 24);
        ISSUE8(B, 40);
        WAITBANK(A, 8);  CONS8(A, 32);
        ISSUE8(A, 48);
        WAITBANK(B, 8);  CONS8(B, 40);
        ISSUE8(B, 56);
        WAITBANK(A, 8);  CONS8(A, 48);
        WAITBANK(B, 0);  CONS8(B, 56);
    }
    __syncthreads();

    // epilogue: out[bucket rows] = acc + bias (coalesced float4)
    const int row0  = b * BROWS;
    const int nrows = min(BROWS, N_NODES - row0);
    const int nf4   = nrows * 16;
    const float4 bb = ((const float4*)bias)[t & 15];
    float4* out4 = (float4*)(out + (long)row0 * OUT_F);
    for (int i = t; i < nf4; i += 256) {
        float4 a = acc4[i];
        out4[i] = make_float4(a.x + bb.x, a.y + bb.y, a.z + bb.z, a.w + bb.w);
    }
}

// ===========================================================================
// Fallback path (ws too small): bias-init + atomic scatter
// ===========================================================================
__global__ __launch_bounds__(256) void bias_init_kernel(
    float* __restrict__ out, const float* __restrict__ bias, int total4)
{
    const float4* b4 = (const float4*)bias;
    float4* o4 = (float4*)out;
    int i = blockIdx.x * blockDim.x + threadIdx.x;
    int stride = gridDim.x * blockDim.x;
    for (; i < total4; i += stride)
        o4[i] = b4[i & 15];
}

__global__ __launch_bounds__(256) void scatter_kernel(
    const float* __restrict__ vals, const int* __restrict__ rows,
    const int* __restrict__ cols, const float* __restrict__ support,
    float* __restrict__ out, int nE)
{
    const int e = blockIdx.x * 4 + (threadIdx.x >> 6);
    if (e >= nE) return;
    const int f = threadIdx.x & 63;
    const float m = vals[e] * support[(long)cols[e] * OUT_F + f];
    atomicAdd(&out[(long)rows[e] * OUT_F + f], m);
}

// ===========================================================================
extern "C" void kernel_launch(void* const* d_in, const int* in_sizes, int n_in,
                              void* d_out, int out_size, void* d_ws, size_t ws_size,
                              hipStream_t stream) {
    const float* input    = (const float*)d_in[0];
    const float* weights  = (const float*)d_in[1];
    const float* bias     = (const float*)d_in[2];
    const float* adj_vals = (const float*)d_in[3];
    const int*   adj_rows = (const int*)d_in[4];
    const int*   adj_cols = (const int*)d_in[5];
    const int nE = in_sizes[3];

    float* out = (float*)d_out;

    // workspace layout (16B-aligned offsets)
    char* ws = (char*)d_ws;
    const size_t off_support = 0;                      // N*64 floats = 25.6 MB
    const size_t off_base    = 25600000;               // (NB+1) ints
    const size_t off_cursor  = off_base + 6400;        // NB ints
    const size_t off_binned  = off_cursor + 6400;      // nE uint2
    const size_t required    = off_binned + (size_t)nE * 8;

    float* support = (float*)(ws + off_support);
    int*   bbase   = (int*)  (ws + off_base);
    int*   cursor  = (int*)  (ws + off_cursor);
    uint2* binned  = (uint2*)(ws + off_binned);

    // 1) support = input @ W
    hipLaunchKernelGGL(gemm_kernel, dim3((N_NODES + 63) / 64), dim3(256), 0,
                       stream, input, weights, support);

    if (ws_size >= required) {
        // 2) cursor (as counts) = 0
        hipLaunchKernelGGL(zero_kernel, dim3((NB + 255) / 256), dim3(256),
                           0, stream, cursor, NB);
        // 3) per-bucket counts
        hipLaunchKernelGGL(count_kernel, dim3(256), dim3(256), 0, stream,
                           adj_rows, cursor, nE);
        // 4) scan -> base, cursor
        hipLaunchKernelGGL(scan_kernel, dim3(1), dim3(256), 0, stream,
                           cursor, bbase, cursor, nE);
        // 5) bin edges by bucket
        hipLaunchKernelGGL(bin_kernel, dim3((nE + BIN_TILE - 1) / BIN_TILE),
                           dim3(256), 0, stream,
                           adj_rows, adj_cols, adj_vals, cursor, binned, nE);
        // 6) per-bucket LDS accumulate + bias -> out
        hipLaunchKernelGGL(bucket_spmm, dim3(NB), dim3(256), 0, stream,
                           bbase, binned, support, bias, out);
    } else {
        hipLaunchKernelGGL(bias_init_kernel, dim3(2048), dim3(256), 0, stream,
                           out, bias, N_NODES * OUT_F / 4);
        hipLaunchKernelGGL(scatter_kernel, dim3((nE + 3) / 4), dim3(256),
                           0, stream, adj_vals, adj_rows, adj_cols, support,
                           out, nE);
    }
}

// Round 8
// 192.359 us; speedup vs baseline: 3.8482x; 3.8482x over previous
//
#include <hip/hip_runtime.h>
#include <hip/hip_bf16.h>

#define N_NODES 100000
#define IN_F 128
#define OUT_F 64
#define BROWS 64                  // rows per bucket
#define NB 1563                   // ceil(100000/64)
#define BIN_TILE 2048             // edges per bin tile (8 per thread)
#define CSR_CAP 8192              // max edges staged per bucket (64 KB LDS)

// ===========================================================================
// Kernel 1: support = input @ W    [N,128] x [128,64] -> [N,64]
// lane = row, A in LDS [64][129], wave-uniform W loads (scalar path)
// ===========================================================================
__global__ __launch_bounds__(256) void gemm_kernel(
    const float* __restrict__ in, const float* __restrict__ W,
    float* __restrict__ support)
{
    __shared__ float Alds[64 * 129];
    const int t = threadIdx.x;
    const long row0 = (long)blockIdx.x * 64;

    #pragma unroll
    for (int i = 0; i < 8; ++i) {
        int fi = t + i * 256;
        int r  = fi >> 5;
        int k4 = (fi & 31) << 2;
        float4 v = make_float4(0.f, 0.f, 0.f, 0.f);
        if (row0 + r < N_NODES)
            v = *(const float4*)(in + (row0 + r) * IN_F + k4);
        Alds[r * 129 + k4 + 0] = v.x;
        Alds[r * 129 + k4 + 1] = v.y;
        Alds[r * 129 + k4 + 2] = v.z;
        Alds[r * 129 + k4 + 3] = v.w;
    }
    __syncthreads();

    const int lane = t & 63;
    const int c0   = __builtin_amdgcn_readfirstlane((t >> 6) << 4);
    const float* __restrict__ Wp = W + c0;

    float acc[16];
    #pragma unroll
    for (int i = 0; i < 16; ++i) acc[i] = 0.f;

    const float* Ar = Alds + lane * 129;
    for (int k = 0; k < IN_F; ++k) {
        const float a = Ar[k];
        const float4 w0 = *(const float4*)(Wp + k * OUT_F + 0);
        const float4 w1 = *(const float4*)(Wp + k * OUT_F + 4);
        const float4 w2 = *(const float4*)(Wp + k * OUT_F + 8);
        const float4 w3 = *(const float4*)(Wp + k * OUT_F + 12);
        acc[0]  = fmaf(a, w0.x, acc[0]);  acc[1]  = fmaf(a, w0.y, acc[1]);
        acc[2]  = fmaf(a, w0.z, acc[2]);  acc[3]  = fmaf(a, w0.w, acc[3]);
        acc[4]  = fmaf(a, w1.x, acc[4]);  acc[5]  = fmaf(a, w1.y, acc[5]);
        acc[6]  = fmaf(a, w1.z, acc[6]);  acc[7]  = fmaf(a, w1.w, acc[7]);
        acc[8]  = fmaf(a, w2.x, acc[8]);  acc[9]  = fmaf(a, w2.y, acc[9]);
        acc[10] = fmaf(a, w2.z, acc[10]); acc[11] = fmaf(a, w2.w, acc[11]);
        acc[12] = fmaf(a, w3.x, acc[12]); acc[13] = fmaf(a, w3.y, acc[13]);
        acc[14] = fmaf(a, w3.z, acc[14]); acc[15] = fmaf(a, w3.w, acc[15]);
    }

    const long orow = row0 + lane;
    if (orow < N_NODES) {
        float* o = support + orow * OUT_F + c0;
        *(float4*)(o + 0)  = make_float4(acc[0],  acc[1],  acc[2],  acc[3]);
        *(float4*)(o + 4)  = make_float4(acc[4],  acc[5],  acc[6],  acc[7]);
        *(float4*)(o + 8)  = make_float4(acc[8],  acc[9],  acc[10], acc[11]);
        *(float4*)(o + 12) = make_float4(acc[12], acc[13], acc[14], acc[15]);
    }
}

// ===========================================================================
__global__ __launch_bounds__(256) void zero_kernel(int* __restrict__ p, int n)
{
    int i = blockIdx.x * 256 + threadIdx.x;
    if (i < n) p[i] = 0;
}

// ===========================================================================
// B1: per-bucket edge counts (LDS-aggregated histogram -> global add)
// ===========================================================================
__global__ __launch_bounds__(256) void count_kernel(
    const int* __restrict__ rows, int* __restrict__ cnt, int nE)
{
    __shared__ int hist[NB];
    const int t = threadIdx.x;
    for (int i = t; i < NB; i += 256) hist[i] = 0;
    __syncthreads();

    for (int e = blockIdx.x * 256 + t; e < nE; e += gridDim.x * 256)
        atomicAdd(&hist[rows[e] >> 6], 1);
    __syncthreads();

    for (int i = t; i < NB; i += 256) {
        int h = hist[i];
        if (h) atomicAdd(&cnt[i], h);
    }
}

// ===========================================================================
// B2: exclusive scan of NB counts (single block, 8 elems/thread).
// ===========================================================================
__global__ __launch_bounds__(256) void scan_kernel(
    const int* __restrict__ cnt, int* __restrict__ base,
    int* __restrict__ cursor, int nE)
{
    __shared__ int lds[256];
    const int t = threadIdx.x;
    const int i0 = t * 8;
    int c[8];
    int tot = 0;
    #pragma unroll
    for (int k = 0; k < 8; ++k) {
        c[k] = (i0 + k < NB) ? cnt[i0 + k] : 0;
        tot += c[k];
    }

    lds[t] = tot;
    __syncthreads();
    int sum = tot;
    #pragma unroll
    for (int off = 1; off < 256; off <<= 1) {
        int y = (t >= off) ? lds[t - off] : 0;
        __syncthreads();
        sum += y;
        lds[t] = sum;
        __syncthreads();
    }
    int run = sum - tot;

    #pragma unroll
    for (int k = 0; k < 8; ++k) {
        if (i0 + k < NB) { base[i0 + k] = run; cursor[i0 + k] = run; }
        run += c[k];
    }
    if (t == 0) base[NB] = nE;
}

// ===========================================================================
// B3: bin edges into bucket-grouped array (LDS hist -> rank; clustered writes)
// payload: x = (row&63)<<17 | col (col < 2^17), y = bits of val.
// ===========================================================================
__global__ __launch_bounds__(256) void bin_kernel(
    const int* __restrict__ rows, const int* __restrict__ cols,
    const float* __restrict__ vals, int* __restrict__ cursor,
    uint2* __restrict__ binned, int nE)
{
    __shared__ int hist[NB];
    __shared__ int lbase[NB];
    const int t  = threadIdx.x;
    const int tb = blockIdx.x * BIN_TILE;

    for (int i = t; i < NB; i += 256) hist[i] = 0;
    __syncthreads();

    int myr[8], myrank[8];
    #pragma unroll
    for (int i = 0; i < 8; ++i) {
        int e = tb + i * 256 + t;
        if (e < nE) {
            int r = rows[e];
            myr[i] = r;
            myrank[i] = atomicAdd(&hist[r >> 6], 1);
        } else myr[i] = -1;
    }
    __syncthreads();

    for (int i = t; i < NB; i += 256) {
        int h = hist[i];
        lbase[i] = h ? atomicAdd(&cursor[i], h) : 0;
    }
    __syncthreads();

    #pragma unroll
    for (int i = 0; i < 8; ++i) {
        int e = tb + i * 256 + t;
        if (e < nE) {
            int r = myr[i];
            unsigned pack = ((unsigned)(r & (BROWS - 1)) << 17) | (unsigned)cols[e];
            binned[lbase[r >> 6] + myrank[i]] =
                make_uint2(pack, __float_as_uint(vals[e]));
        }
    }
}

// ===========================================================================
// B4 (new): per-bucket CSR-ify IN PLACE. One block per bucket: stage the
// bucket's edges in LDS, histogram the 64 rows, wave-scan, write back
// row-sorted into the same contiguous region (all traffic bucket-local,
// L2-clustered). Emits row_start. Sentinel path for n > CSR_CAP (never
// triggers at mean 1024, sigma ~32): row_start = -(s)-1 -> spmm filters.
// ===========================================================================
__global__ __launch_bounds__(256) void csr_kernel(
    const int* __restrict__ base, uint2* __restrict__ binned,
    int* __restrict__ row_start)
{
    __shared__ uint2 stage[CSR_CAP];     // 64 KB
    __shared__ int rh[BROWS], rc[BROWS];
    const int t = threadIdx.x;
    const int b = blockIdx.x;
    const int s = base[b], e = base[b + 1];
    const int n = e - s;

    if (t < BROWS) rh[t] = 0;
    __syncthreads();

    if (n <= CSR_CAP) {
        for (int i = t; i < n; i += 256) {
            uint2 p = binned[s + i];
            stage[i] = p;
            atomicAdd(&rh[p.x >> 17], 1);
        }
        __syncthreads();
        if (t < BROWS) {
            int v = rh[t];
            int inc = v;
            #pragma unroll
            for (int off = 1; off < BROWS; off <<= 1) {
                int y = __shfl_up(inc, off, 64);
                if ((t & 63) >= off) inc += y;
            }
            int excl = inc - v;
            row_start[b * BROWS + t] = s + excl;
            rc[t] = excl;
        }
        __syncthreads();
        for (int i = t; i < n; i += 256) {
            uint2 p = stage[i];
            int pos = atomicAdd(&rc[p.x >> 17], 1);
            binned[s + pos] = p;
        }
    } else {
        // sentinel: spmm will filter the whole bucket per row
        if (t < BROWS) row_start[b * BROWS + t] = -s - 1;
    }
}

// ===========================================================================
// B5: per-row wave gather spmm (round-2 structure: the measured-fast one).
// One wave per row, lane = feature; 25K blocks -> 100K waves.
//   out[r][f] = bias[f] + sum_j val[j] * support[col[j]][f]
// ===========================================================================
__global__ __launch_bounds__(256) void spmm_row(
    const int* __restrict__ row_start, const uint2* __restrict__ binned,
    const float* __restrict__ support, const float* __restrict__ bias,
    float* __restrict__ out)
{
    const int wid  = threadIdx.x >> 6;
    const int lane = threadIdx.x & 63;
    const int r    = blockIdx.x * 4 + wid;
    if (r >= N_NODES) return;

    const int s0 = row_start[r];
    const int s1 = row_start[r + 1];
    const bool filt = (s0 < 0);
    const int s = filt ? (-s0 - 1) : s0;
    const int e = (s1 < 0) ? (-s1 - 1) : s1;

    float acc = bias[lane];
    if (!filt) {
        int j = s;
        for (; j + 3 < e; j += 4) {
            uint2 p0 = binned[j + 0];
            uint2 p1 = binned[j + 1];
            uint2 p2 = binned[j + 2];
            uint2 p3 = binned[j + 3];
            float g0 = support[(size_t)(p0.x & 131071u) * OUT_F + lane];
            float g1 = support[(size_t)(p1.x & 131071u) * OUT_F + lane];
            float g2 = support[(size_t)(p2.x & 131071u) * OUT_F + lane];
            float g3 = support[(size_t)(p3.x & 131071u) * OUT_F + lane];
            acc = fmaf(__uint_as_float(p0.y), g0, acc);
            acc = fmaf(__uint_as_float(p1.y), g1, acc);
            acc = fmaf(__uint_as_float(p2.y), g2, acc);
            acc = fmaf(__uint_as_float(p3.y), g3, acc);
        }
        for (; j < e; ++j) {
            uint2 p = binned[j];
            acc = fmaf(__uint_as_float(p.y),
                       support[(size_t)(p.x & 131071u) * OUT_F + lane], acc);
        }
    } else {
        const unsigned rr = (unsigned)(r & (BROWS - 1));
        for (int j = s; j < e; ++j) {
            uint2 p = binned[j];
            if ((p.x >> 17) == rr)
                acc = fmaf(__uint_as_float(p.y),
                           support[(size_t)(p.x & 131071u) * OUT_F + lane], acc);
        }
    }
    out[(size_t)r * OUT_F + lane] = acc;
}

// ===========================================================================
// Fallback path (ws too small): bias-init + atomic scatter
// ===========================================================================
__global__ __launch_bounds__(256) void bias_init_kernel(
    float* __restrict__ out, const float* __restrict__ bias, int total4)
{
    const float4* b4 = (const float4*)bias;
    float4* o4 = (float4*)out;
    int i = blockIdx.x * blockDim.x + threadIdx.x;
    int stride = gridDim.x * blockDim.x;
    for (; i < total4; i += stride)
        o4[i] = b4[i & 15];
}

__global__ __launch_bounds__(256) void scatter_kernel(
    const float* __restrict__ vals, const int* __restrict__ rows,
    const int* __restrict__ cols, const float* __restrict__ support,
    float* __restrict__ out, int nE)
{
    const int e = blockIdx.x * 4 + (threadIdx.x >> 6);
    if (e >= nE) return;
    const int f = threadIdx.x & 63;
    const float m = vals[e] * support[(long)cols[e] * OUT_F + f];
    atomicAdd(&out[(long)rows[e] * OUT_F + f], m);
}

// ===========================================================================
extern "C" void kernel_launch(void* const* d_in, const int* in_sizes, int n_in,
                              void* d_out, int out_size, void* d_ws, size_t ws_size,
                              hipStream_t stream) {
    const float* input    = (const float*)d_in[0];
    const float* weights  = (const float*)d_in[1];
    const float* bias     = (const float*)d_in[2];
    const float* adj_vals = (const float*)d_in[3];
    const int*   adj_rows = (const int*)d_in[4];
    const int*   adj_cols = (const int*)d_in[5];
    const int nE = in_sizes[3];

    float* out = (float*)d_out;

    // workspace layout (16B-aligned offsets)
    char* ws = (char*)d_ws;
    const size_t off_support = 0;                       // N*64 floats = 25.6 MB
    const size_t off_base    = 25600000;                // (NB+1) ints
    const size_t off_cursor  = off_base + 6400;         // NB ints
    const size_t off_rstart  = off_cursor + 6400;       // NB*64+1 ints (~400 KB)
    const size_t off_binned  = off_rstart + 400384;     // nE uint2
    const size_t required    = off_binned + (size_t)nE * 8;

    float* support   = (float*)(ws + off_support);
    int*   bbase     = (int*)  (ws + off_base);
    int*   cursor    = (int*)  (ws + off_cursor);
    int*   row_start = (int*)  (ws + off_rstart);
    uint2* binned    = (uint2*)(ws + off_binned);

    // 1) support = input @ W
    hipLaunchKernelGGL(gemm_kernel, dim3((N_NODES + 63) / 64), dim3(256), 0,
                       stream, input, weights, support);

    if (ws_size >= required) {
        // 2) cursor (as counts) = 0
        hipLaunchKernelGGL(zero_kernel, dim3((NB + 255) / 256), dim3(256),
                           0, stream, cursor, NB);
        // 3) per-bucket counts
        hipLaunchKernelGGL(count_kernel, dim3(256), dim3(256), 0, stream,
                           adj_rows, cursor, nE);
        // 4) scan -> base, cursor
        hipLaunchKernelGGL(scan_kernel, dim3(1), dim3(256), 0, stream,
                           cursor, bbase, cursor, nE);
        // 5) bin edges by bucket (clustered writes)
        hipLaunchKernelGGL(bin_kernel, dim3((nE + BIN_TILE - 1) / BIN_TILE),
                           dim3(256), 0, stream,
                           adj_rows, adj_cols, adj_vals, cursor, binned, nE);
        // 6) per-bucket in-place row sort -> CSR
        hipLaunchKernelGGL(csr_kernel, dim3(NB), dim3(256), 0, stream,
                           bbase, binned, row_start);
        // 7) per-row wave gather + bias -> out
        hipLaunchKernelGGL(spmm_row, dim3((N_NODES + 3) / 4), dim3(256),
                           0, stream, row_start, binned, support, bias, out);
    } else {
        hipLaunchKernelGGL(bias_init_kernel, dim3(2048), dim3(256), 0, stream,
                           out, bias, N_NODES * OUT_F / 4);
        hipLaunchKernelGGL(scatter_kernel, dim3((nE + 3) / 4), dim3(256),
                           0, stream, adj_vals, adj_rows, adj_cols, support,
                           out, nE);
    }
}

// Round 9
// 188.750 us; speedup vs baseline: 3.9218x; 1.0191x over previous
//
#include <hip/hip_runtime.h>
#include <hip/hip_bf16.h>

#define N_NODES 100000
#define IN_F 128
#define OUT_F 64
#define BROWS 64                  // rows per bucket
#define NB 1563                   // ceil(100000/64)
#define BIN_TILE 2048             // edges per bin tile (8 per thread)
#define CSR_CAP 8192              // max edges staged per bucket (64 KB LDS)

// RNE float -> bf16 (bits)
__device__ __forceinline__ unsigned short f2bf(float x) {
    unsigned u = __float_as_uint(x);
    u += 0x7FFFu + ((u >> 16) & 1u);
    return (unsigned short)(u >> 16);
}
// bf16 (bits) -> float (exact)
__device__ __forceinline__ float bf2f(unsigned short s) {
    return __uint_as_float(((unsigned)s) << 16);
}

// ===========================================================================
// Kernel 1: support = bf16(input @ W)    [N,128] x [128,64] -> [N,64] bf16
// lane = row, A in LDS [64][129], wave-uniform W loads (scalar path).
// Epilogue packs 16 bf16 = 32 B -> two uint4 stores.
// ===========================================================================
__global__ __launch_bounds__(256) void gemm_kernel(
    const float* __restrict__ in, const float* __restrict__ W,
    unsigned short* __restrict__ support)
{
    __shared__ float Alds[64 * 129];
    const int t = threadIdx.x;
    const long row0 = (long)blockIdx.x * 64;

    #pragma unroll
    for (int i = 0; i < 8; ++i) {
        int fi = t + i * 256;
        int r  = fi >> 5;
        int k4 = (fi & 31) << 2;
        float4 v = make_float4(0.f, 0.f, 0.f, 0.f);
        if (row0 + r < N_NODES)
            v = *(const float4*)(in + (row0 + r) * IN_F + k4);
        Alds[r * 129 + k4 + 0] = v.x;
        Alds[r * 129 + k4 + 1] = v.y;
        Alds[r * 129 + k4 + 2] = v.z;
        Alds[r * 129 + k4 + 3] = v.w;
    }
    __syncthreads();

    const int lane = t & 63;
    const int c0   = __builtin_amdgcn_readfirstlane((t >> 6) << 4);
    const float* __restrict__ Wp = W + c0;

    float acc[16];
    #pragma unroll
    for (int i = 0; i < 16; ++i) acc[i] = 0.f;

    const float* Ar = Alds + lane * 129;
    for (int k = 0; k < IN_F; ++k) {
        const float a = Ar[k];
        const float4 w0 = *(const float4*)(Wp + k * OUT_F + 0);
        const float4 w1 = *(const float4*)(Wp + k * OUT_F + 4);
        const float4 w2 = *(const float4*)(Wp + k * OUT_F + 8);
        const float4 w3 = *(const float4*)(Wp + k * OUT_F + 12);
        acc[0]  = fmaf(a, w0.x, acc[0]);  acc[1]  = fmaf(a, w0.y, acc[1]);
        acc[2]  = fmaf(a, w0.z, acc[2]);  acc[3]  = fmaf(a, w0.w, acc[3]);
        acc[4]  = fmaf(a, w1.x, acc[4]);  acc[5]  = fmaf(a, w1.y, acc[5]);
        acc[6]  = fmaf(a, w1.z, acc[6]);  acc[7]  = fmaf(a, w1.w, acc[7]);
        acc[8]  = fmaf(a, w2.x, acc[8]);  acc[9]  = fmaf(a, w2.y, acc[9]);
        acc[10] = fmaf(a, w2.z, acc[10]); acc[11] = fmaf(a, w2.w, acc[11]);
        acc[12] = fmaf(a, w3.x, acc[12]); acc[13] = fmaf(a, w3.y, acc[13]);
        acc[14] = fmaf(a, w3.z, acc[14]); acc[15] = fmaf(a, w3.w, acc[15]);
    }

    const long orow = row0 + lane;
    if (orow < N_NODES) {
        unsigned up[8];
        #pragma unroll
        for (int i = 0; i < 8; ++i)
            up[i] = (unsigned)f2bf(acc[2 * i]) |
                    ((unsigned)f2bf(acc[2 * i + 1]) << 16);
        unsigned short* o = support + orow * OUT_F + c0;   // 32B-aligned
        *(uint4*)(o + 0) = make_uint4(up[0], up[1], up[2], up[3]);
        *(uint4*)(o + 8) = make_uint4(up[4], up[5], up[6], up[7]);
    }
}

// ===========================================================================
__global__ __launch_bounds__(256) void zero_kernel(int* __restrict__ p, int n)
{
    int i = blockIdx.x * 256 + threadIdx.x;
    if (i < n) p[i] = 0;
}

// ===========================================================================
// B1: per-bucket edge counts (LDS-aggregated histogram -> global add)
// ===========================================================================
__global__ __launch_bounds__(256) void count_kernel(
    const int* __restrict__ rows, int* __restrict__ cnt, int nE)
{
    __shared__ int hist[NB];
    const int t = threadIdx.x;
    for (int i = t; i < NB; i += 256) hist[i] = 0;
    __syncthreads();

    for (int e = blockIdx.x * 256 + t; e < nE; e += gridDim.x * 256)
        atomicAdd(&hist[rows[e] >> 6], 1);
    __syncthreads();

    for (int i = t; i < NB; i += 256) {
        int h = hist[i];
        if (h) atomicAdd(&cnt[i], h);
    }
}

// ===========================================================================
// B2: exclusive scan of NB counts (single block, 8 elems/thread).
// ===========================================================================
__global__ __launch_bounds__(256) void scan_kernel(
    const int* __restrict__ cnt, int* __restrict__ base,
    int* __restrict__ cursor, int nE)
{
    __shared__ int lds[256];
    const int t = threadIdx.x;
    const int i0 = t * 8;
    int c[8];
    int tot = 0;
    #pragma unroll
    for (int k = 0; k < 8; ++k) {
        c[k] = (i0 + k < NB) ? cnt[i0 + k] : 0;
        tot += c[k];
    }

    lds[t] = tot;
    __syncthreads();
    int sum = tot;
    #pragma unroll
    for (int off = 1; off < 256; off <<= 1) {
        int y = (t >= off) ? lds[t - off] : 0;
        __syncthreads();
        sum += y;
        lds[t] = sum;
        __syncthreads();
    }
    int run = sum - tot;

    #pragma unroll
    for (int k = 0; k < 8; ++k) {
        if (i0 + k < NB) { base[i0 + k] = run; cursor[i0 + k] = run; }
        run += c[k];
    }
    if (t == 0) base[NB] = nE;
}

// ===========================================================================
// B3: bin edges into bucket-grouped array (LDS hist -> rank; clustered writes)
// payload: x = (row&63)<<17 | col (col < 2^17), y = bits of val.
// ===========================================================================
__global__ __launch_bounds__(256) void bin_kernel(
    const int* __restrict__ rows, const int* __restrict__ cols,
    const float* __restrict__ vals, int* __restrict__ cursor,
    uint2* __restrict__ binned, int nE)
{
    __shared__ int hist[NB];
    __shared__ int lbase[NB];
    const int t  = threadIdx.x;
    const int tb = blockIdx.x * BIN_TILE;

    for (int i = t; i < NB; i += 256) hist[i] = 0;
    __syncthreads();

    int myr[8], myrank[8];
    #pragma unroll
    for (int i = 0; i < 8; ++i) {
        int e = tb + i * 256 + t;
        if (e < nE) {
            int r = rows[e];
            myr[i] = r;
            myrank[i] = atomicAdd(&hist[r >> 6], 1);
        } else myr[i] = -1;
    }
    __syncthreads();

    for (int i = t; i < NB; i += 256) {
        int h = hist[i];
        lbase[i] = h ? atomicAdd(&cursor[i], h) : 0;
    }
    __syncthreads();

    #pragma unroll
    for (int i = 0; i < 8; ++i) {
        int e = tb + i * 256 + t;
        if (e < nE) {
            int r = myr[i];
            unsigned pack = ((unsigned)(r & (BROWS - 1)) << 17) | (unsigned)cols[e];
            binned[lbase[r >> 6] + myrank[i]] =
                make_uint2(pack, __float_as_uint(vals[e]));
        }
    }
}

// ===========================================================================
// B4: per-bucket CSR-ify IN PLACE (bucket-local traffic, L2-clustered).
// Sentinel path for n > CSR_CAP: row_start = -s-1 -> spmm filters.
// ===========================================================================
__global__ __launch_bounds__(256) void csr_kernel(
    const int* __restrict__ base, uint2* __restrict__ binned,
    int* __restrict__ row_start)
{
    __shared__ uint2 stage[CSR_CAP];     // 64 KB
    __shared__ int rh[BROWS], rc[BROWS];
    const int t = threadIdx.x;
    const int b = blockIdx.x;
    const int s = base[b], e = base[b + 1];
    const int n = e - s;

    if (t < BROWS) rh[t] = 0;
    __syncthreads();

    if (n <= CSR_CAP) {
        for (int i = t; i < n; i += 256) {
            uint2 p = binned[s + i];
            stage[i] = p;
            atomicAdd(&rh[p.x >> 17], 1);
        }
        __syncthreads();
        if (t < BROWS) {
            int v = rh[t];
            int inc = v;
            #pragma unroll
            for (int off = 1; off < BROWS; off <<= 1) {
                int y = __shfl_up(inc, off, 64);
                if ((t & 63) >= off) inc += y;
            }
            int excl = inc - v;
            row_start[b * BROWS + t] = s + excl;
            rc[t] = excl;
        }
        __syncthreads();
        for (int i = t; i < n; i += 256) {
            uint2 p = stage[i];
            int pos = atomicAdd(&rc[p.x >> 17], 1);
            binned[s + pos] = p;
        }
    } else {
        if (t < BROWS) row_start[b * BROWS + t] = -s - 1;
    }
}

// ===========================================================================
// B5: per-row wave gather spmm. One wave per row, lane = feature.
// support is bf16: 128 B gather per edge (2 cache lines, was 4).
// ===========================================================================
__global__ __launch_bounds__(256) void spmm_row(
    const int* __restrict__ row_start, const uint2* __restrict__ binned,
    const unsigned short* __restrict__ support, const float* __restrict__ bias,
    float* __restrict__ out)
{
    const int wid  = threadIdx.x >> 6;
    const int lane = threadIdx.x & 63;
    const int r    = blockIdx.x * 4 + wid;
    if (r >= N_NODES) return;

    const int s0 = row_start[r];
    const int s1 = row_start[r + 1];
    const bool filt = (s0 < 0);
    const int s = filt ? (-s0 - 1) : s0;
    const int e = (s1 < 0) ? (-s1 - 1) : s1;

    float acc = bias[lane];
    if (!filt) {
        int j = s;
        for (; j + 3 < e; j += 4) {
            uint2 p0 = binned[j + 0];
            uint2 p1 = binned[j + 1];
            uint2 p2 = binned[j + 2];
            uint2 p3 = binned[j + 3];
            float g0 = bf2f(support[((size_t)(p0.x & 131071u) << 6) + lane]);
            float g1 = bf2f(support[((size_t)(p1.x & 131071u) << 6) + lane]);
            float g2 = bf2f(support[((size_t)(p2.x & 131071u) << 6) + lane]);
            float g3 = bf2f(support[((size_t)(p3.x & 131071u) << 6) + lane]);
            acc = fmaf(__uint_as_float(p0.y), g0, acc);
            acc = fmaf(__uint_as_float(p1.y), g1, acc);
            acc = fmaf(__uint_as_float(p2.y), g2, acc);
            acc = fmaf(__uint_as_float(p3.y), g3, acc);
        }
        for (; j < e; ++j) {
            uint2 p = binned[j];
            acc = fmaf(__uint_as_float(p.y),
                       bf2f(support[((size_t)(p.x & 131071u) << 6) + lane]), acc);
        }
    } else {
        const unsigned rr = (unsigned)(r & (BROWS - 1));
        for (int j = s; j < e; ++j) {
            uint2 p = binned[j];
            if ((p.x >> 17) == rr)
                acc = fmaf(__uint_as_float(p.y),
                           bf2f(support[((size_t)(p.x & 131071u) << 6) + lane]),
                           acc);
        }
    }
    out[(size_t)r * OUT_F + lane] = acc;
}

// ===========================================================================
// Fallback path (ws too small): bias-init + atomic scatter (bf16 support)
// ===========================================================================
__global__ __launch_bounds__(256) void bias_init_kernel(
    float* __restrict__ out, const float* __restrict__ bias, int total4)
{
    const float4* b4 = (const float4*)bias;
    float4* o4 = (float4*)out;
    int i = blockIdx.x * blockDim.x + threadIdx.x;
    int stride = gridDim.x * blockDim.x;
    for (; i < total4; i += stride)
        o4[i] = b4[i & 15];
}

__global__ __launch_bounds__(256) void scatter_kernel(
    const float* __restrict__ vals, const int* __restrict__ rows,
    const int* __restrict__ cols, const unsigned short* __restrict__ support,
    float* __restrict__ out, int nE)
{
    const int e = blockIdx.x * 4 + (threadIdx.x >> 6);
    if (e >= nE) return;
    const int f = threadIdx.x & 63;
    const float m = vals[e] * bf2f(support[(size_t)cols[e] * OUT_F + f]);
    atomicAdd(&out[(size_t)rows[e] * OUT_F + f], m);
}

// ===========================================================================
extern "C" void kernel_launch(void* const* d_in, const int* in_sizes, int n_in,
                              void* d_out, int out_size, void* d_ws, size_t ws_size,
                              hipStream_t stream) {
    const float* input    = (const float*)d_in[0];
    const float* weights  = (const float*)d_in[1];
    const float* bias     = (const float*)d_in[2];
    const float* adj_vals = (const float*)d_in[3];
    const int*   adj_rows = (const int*)d_in[4];
    const int*   adj_cols = (const int*)d_in[5];
    const int nE = in_sizes[3];

    float* out = (float*)d_out;

    // workspace layout (16B-aligned offsets)
    char* ws = (char*)d_ws;
    const size_t off_support = 0;                       // N*64 bf16 = 12.8 MB
    const size_t off_base    = 12800000;                // (NB+1) ints
    const size_t off_cursor  = off_base + 6400;         // NB ints
    const size_t off_rstart  = off_cursor + 6400;       // NB*64+1 ints (~400 KB)
    const size_t off_binned  = off_rstart + 400384;     // nE uint2
    const size_t required    = off_binned + (size_t)nE * 8;

    unsigned short* support = (unsigned short*)(ws + off_support);
    int*   bbase     = (int*)  (ws + off_base);
    int*   cursor    = (int*)  (ws + off_cursor);
    int*   row_start = (int*)  (ws + off_rstart);
    uint2* binned    = (uint2*)(ws + off_binned);

    // 1) support = bf16(input @ W)
    hipLaunchKernelGGL(gemm_kernel, dim3((N_NODES + 63) / 64), dim3(256), 0,
                       stream, input, weights, support);

    if (ws_size >= required) {
        // 2) cursor (as counts) = 0
        hipLaunchKernelGGL(zero_kernel, dim3((NB + 255) / 256), dim3(256),
                           0, stream, cursor, NB);
        // 3) per-bucket counts
        hipLaunchKernelGGL(count_kernel, dim3(256), dim3(256), 0, stream,
                           adj_rows, cursor, nE);
        // 4) scan -> base, cursor
        hipLaunchKernelGGL(scan_kernel, dim3(1), dim3(256), 0, stream,
                           cursor, bbase, cursor, nE);
        // 5) bin edges by bucket (clustered writes)
        hipLaunchKernelGGL(bin_kernel, dim3((nE + BIN_TILE - 1) / BIN_TILE),
                           dim3(256), 0, stream,
                           adj_rows, adj_cols, adj_vals, cursor, binned, nE);
        // 6) per-bucket in-place row sort -> CSR
        hipLaunchKernelGGL(csr_kernel, dim3(NB), dim3(256), 0, stream,
                           bbase, binned, row_start);
        // 7) per-row wave gather + bias -> out
        hipLaunchKernelGGL(spmm_row, dim3((N_NODES + 3) / 4), dim3(256),
                           0, stream, row_start, binned, support, bias, out);
    } else {
        hipLaunchKernelGGL(bias_init_kernel, dim3(2048), dim3(256), 0, stream,
                           out, bias, N_NODES * OUT_F / 4);
        hipLaunchKernelGGL(scatter_kernel, dim3((nE + 3) / 4), dim3(256),
                           0, stream, adj_vals, adj_rows, adj_cols, support,
                           out, nE);
    }
}

// Round 10
// 134.271 us; speedup vs baseline: 5.5130x; 1.4057x over previous
//
#include <hip/hip_runtime.h>
#include <hip/hip_bf16.h>

#define N_NODES 100000
#define IN_F 128
#define OUT_F 64
#define BROWS 64                  // rows per bucket
#define NB 1563                   // ceil(100000/64)
#define BIN_TILE 4096             // edges per bin tile (16 per thread)
#define CSB_CAP 2048              // max edges per bucket in csr_spmm LDS (32 KB)

// RNE float -> bf16 (bits)
__device__ __forceinline__ unsigned short f2bf(float x) {
    unsigned u = __float_as_uint(x);
    u += 0x7FFFu + ((u >> 16) & 1u);
    return (unsigned short)(u >> 16);
}
// bf16 (bits) -> float (exact)
__device__ __forceinline__ float bf2f(unsigned short s) {
    return __uint_as_float(((unsigned)s) << 16);
}

// ===========================================================================
// Kernel A (fused): blocks [0, gemmBlocks) do support = bf16(input @ W);
// blocks [gemmBlocks, gemmBlocks+countBlocks) histogram adj_rows into cnt.
// gemm: lane = row, A in LDS [64][129], wave-uniform W loads (scalar path).
// ===========================================================================
__global__ __launch_bounds__(256) void gemm_count_kernel(
    const float* __restrict__ in, const float* __restrict__ W,
    unsigned short* __restrict__ support,
    const int* __restrict__ rows, int* __restrict__ cnt,
    int nE, int gemmBlocks)
{
    __shared__ float Alds[64 * 129];     // 33 KB
    __shared__ int histL[NB];            // 6.3 KB
    const int t = threadIdx.x;

    if ((int)blockIdx.x >= gemmBlocks) {
        // ---------------- count body ----------------
        for (int i = t; i < NB; i += 256) histL[i] = 0;
        __syncthreads();
        const int cb = blockIdx.x - gemmBlocks;
        for (int e = cb * 256 + t; e < nE; e += 256 * 256)
            atomicAdd(&histL[rows[e] >> 6], 1);
        __syncthreads();
        for (int i = t; i < NB; i += 256) {
            int h = histL[i];
            if (h) atomicAdd(&cnt[i], h);
        }
        return;
    }

    // ---------------- gemm body ----------------
    const long row0 = (long)blockIdx.x * 64;

    #pragma unroll
    for (int i = 0; i < 8; ++i) {
        int fi = t + i * 256;
        int r  = fi >> 5;
        int k4 = (fi & 31) << 2;
        float4 v = make_float4(0.f, 0.f, 0.f, 0.f);
        if (row0 + r < N_NODES)
            v = *(const float4*)(in + (row0 + r) * IN_F + k4);
        Alds[r * 129 + k4 + 0] = v.x;
        Alds[r * 129 + k4 + 1] = v.y;
        Alds[r * 129 + k4 + 2] = v.z;
        Alds[r * 129 + k4 + 3] = v.w;
    }
    __syncthreads();

    const int lane = t & 63;
    const int c0   = __builtin_amdgcn_readfirstlane((t >> 6) << 4);
    const float* __restrict__ Wp = W + c0;

    float acc[16];
    #pragma unroll
    for (int i = 0; i < 16; ++i) acc[i] = 0.f;

    const float* Ar = Alds + lane * 129;
    for (int k = 0; k < IN_F; ++k) {
        const float a = Ar[k];
        const float4 w0 = *(const float4*)(Wp + k * OUT_F + 0);
        const float4 w1 = *(const float4*)(Wp + k * OUT_F + 4);
        const float4 w2 = *(const float4*)(Wp + k * OUT_F + 8);
        const float4 w3 = *(const float4*)(Wp + k * OUT_F + 12);
        acc[0]  = fmaf(a, w0.x, acc[0]);  acc[1]  = fmaf(a, w0.y, acc[1]);
        acc[2]  = fmaf(a, w0.z, acc[2]);  acc[3]  = fmaf(a, w0.w, acc[3]);
        acc[4]  = fmaf(a, w1.x, acc[4]);  acc[5]  = fmaf(a, w1.y, acc[5]);
        acc[6]  = fmaf(a, w1.z, acc[6]);  acc[7]  = fmaf(a, w1.w, acc[7]);
        acc[8]  = fmaf(a, w2.x, acc[8]);  acc[9]  = fmaf(a, w2.y, acc[9]);
        acc[10] = fmaf(a, w2.z, acc[10]); acc[11] = fmaf(a, w2.w, acc[11]);
        acc[12] = fmaf(a, w3.x, acc[12]); acc[13] = fmaf(a, w3.y, acc[13]);
        acc[14] = fmaf(a, w3.z, acc[14]); acc[15] = fmaf(a, w3.w, acc[15]);
    }

    const long orow = row0 + lane;
    if (orow < N_NODES) {
        unsigned up[8];
        #pragma unroll
        for (int i = 0; i < 8; ++i)
            up[i] = (unsigned)f2bf(acc[2 * i]) |
                    ((unsigned)f2bf(acc[2 * i + 1]) << 16);
        unsigned short* o = support + orow * OUT_F + c0;   // 32B-aligned
        *(uint4*)(o + 0) = make_uint4(up[0], up[1], up[2], up[3]);
        *(uint4*)(o + 8) = make_uint4(up[4], up[5], up[6], up[7]);
    }
}

// ===========================================================================
__global__ __launch_bounds__(256) void zero_kernel(int* __restrict__ p, int n)
{
    int i = blockIdx.x * 256 + threadIdx.x;
    if (i < n) p[i] = 0;
}

// ===========================================================================
// B2: exclusive scan of NB counts (single block, 8 elems/thread).
// base <- scan(cnt), cursor <- same, base[NB] = nE.
// ===========================================================================
__global__ __launch_bounds__(256) void scan_kernel(
    const int* __restrict__ cnt, int* __restrict__ base,
    int* __restrict__ cursor, int nE)
{
    __shared__ int lds[256];
    const int t = threadIdx.x;
    const int i0 = t * 8;
    int c[8];
    int tot = 0;
    #pragma unroll
    for (int k = 0; k < 8; ++k) {
        c[k] = (i0 + k < NB) ? cnt[i0 + k] : 0;
        tot += c[k];
    }

    lds[t] = tot;
    __syncthreads();
    int sum = tot;
    #pragma unroll
    for (int off = 1; off < 256; off <<= 1) {
        int y = (t >= off) ? lds[t - off] : 0;
        __syncthreads();
        sum += y;
        lds[t] = sum;
        __syncthreads();
    }
    int run = sum - tot;

    #pragma unroll
    for (int k = 0; k < 8; ++k) {
        if (i0 + k < NB) { base[i0 + k] = run; cursor[i0 + k] = run; }
        run += c[k];
    }
    if (t == 0) base[NB] = nE;
}

// ===========================================================================
// B3: bin edges into bucket-grouped array (LDS hist -> rank; clustered writes)
// payload: x = (row&63)<<17 | col (col < 2^17), y = bits of val.
// ===========================================================================
__global__ __launch_bounds__(256) void bin_kernel(
    const int* __restrict__ rows, const int* __restrict__ cols,
    const float* __restrict__ vals, int* __restrict__ cursor,
    uint2* __restrict__ binned, int nE)
{
    __shared__ int hist[NB];
    __shared__ int lbase[NB];
    const int t  = threadIdx.x;
    const int tb = blockIdx.x * BIN_TILE;

    for (int i = t; i < NB; i += 256) hist[i] = 0;
    __syncthreads();

    int myr[16], myrank[16];
    #pragma unroll
    for (int i = 0; i < 16; ++i) {
        int e = tb + i * 256 + t;
        if (e < nE) {
            int r = rows[e];
            myr[i] = r;
            myrank[i] = atomicAdd(&hist[r >> 6], 1);
        } else myr[i] = -1;
    }
    __syncthreads();

    for (int i = t; i < NB; i += 256) {
        int h = hist[i];
        lbase[i] = h ? atomicAdd(&cursor[i], h) : 0;
    }
    __syncthreads();

    #pragma unroll
    for (int i = 0; i < 16; ++i) {
        int e = tb + i * 256 + t;
        if (e < nE) {
            int r = myr[i];
            unsigned pack = ((unsigned)(r & (BROWS - 1)) << 17) | (unsigned)cols[e];
            binned[lbase[r >> 6] + myrank[i]] =
                make_uint2(pack, __float_as_uint(vals[e]));
        }
    }
}

// ===========================================================================
// B4 (fused csr+spmm): one block (1024 thr = 16 waves) per bucket.
// Stage bucket's edges in LDS, row-sort in LDS (hist + wave scan + rank
// scatter), then 16 waves x 4 rows: per-row gather from bf16 support
// (unroll 8 -> 8 gathers in flight/wave), bias fused, single out write.
// LDS ~33 KB -> 2 blocks/CU (thread-limited) = 32 waves/CU. 25K waves total.
// ===========================================================================
__global__ __launch_bounds__(1024, 2) void csr_spmm(
    const int* __restrict__ base, const uint2* __restrict__ binned,
    const unsigned short* __restrict__ support, const float* __restrict__ bias,
    float* __restrict__ out)
{
    __shared__ uint2 stage[CSB_CAP];     // 16 KB
    __shared__ uint2 sorted[CSB_CAP];    // 16 KB
    __shared__ int rh[BROWS], rs[BROWS + 1], rc[BROWS];
    const int t = threadIdx.x;
    const int b = blockIdx.x;
    const int s = base[b], e = base[b + 1];
    const int n = e - s;
    const int wid  = t >> 6;      // 0..15
    const int lane = t & 63;
    const int row0 = b * BROWS;

    if (t < BROWS) rh[t] = 0;
    __syncthreads();

    if (n <= CSB_CAP) {
        // stage + per-row histogram
        for (int i = t; i < n; i += 1024) {
            uint2 p = binned[s + i];
            stage[i] = p;
            atomicAdd(&rh[p.x >> 17], 1);
        }
        __syncthreads();
        // wave-0 exclusive scan of 64 row counts
        if (t < BROWS) {
            int v = rh[t];
            int inc = v;
            #pragma unroll
            for (int off = 1; off < BROWS; off <<= 1) {
                int y = __shfl_up(inc, off, 64);
                if (t >= off) inc += y;
            }
            rs[t] = inc - v;
            rc[t] = inc - v;
            if (t == BROWS - 1) rs[BROWS] = inc;
        }
        __syncthreads();
        // rank-scatter into sorted[]
        for (int i = t; i < n; i += 1024) {
            uint2 p = stage[i];
            int pos = atomicAdd(&rc[p.x >> 17], 1);
            sorted[pos] = p;
        }
        __syncthreads();

        // spmm: wave wid handles rows [wid*4, wid*4+4)
        #pragma unroll
        for (int q = 0; q < 4; ++q) {
            const int rr = wid * 4 + q;
            const int r  = row0 + rr;
            if (r >= N_NODES) break;
            float acc = bias[lane];
            int j  = rs[rr];
            const int je = rs[rr + 1];
            for (; j + 7 < je; j += 8) {
                uint2 q0 = sorted[j + 0];
                uint2 q1 = sorted[j + 1];
                uint2 q2 = sorted[j + 2];
                uint2 q3 = sorted[j + 3];
                uint2 q4 = sorted[j + 4];
                uint2 q5 = sorted[j + 5];
                uint2 q6 = sorted[j + 6];
                uint2 q7 = sorted[j + 7];
                float g0 = bf2f(support[((size_t)(q0.x & 131071u) << 6) + lane]);
                float g1 = bf2f(support[((size_t)(q1.x & 131071u) << 6) + lane]);
                float g2 = bf2f(support[((size_t)(q2.x & 131071u) << 6) + lane]);
                float g3 = bf2f(support[((size_t)(q3.x & 131071u) << 6) + lane]);
                float g4 = bf2f(support[((size_t)(q4.x & 131071u) << 6) + lane]);
                float g5 = bf2f(support[((size_t)(q5.x & 131071u) << 6) + lane]);
                float g6 = bf2f(support[((size_t)(q6.x & 131071u) << 6) + lane]);
                float g7 = bf2f(support[((size_t)(q7.x & 131071u) << 6) + lane]);
                acc = fmaf(__uint_as_float(q0.y), g0, acc);
                acc = fmaf(__uint_as_float(q1.y), g1, acc);
                acc = fmaf(__uint_as_float(q2.y), g2, acc);
                acc = fmaf(__uint_as_float(q3.y), g3, acc);
                acc = fmaf(__uint_as_float(q4.y), g4, acc);
                acc = fmaf(__uint_as_float(q5.y), g5, acc);
                acc = fmaf(__uint_as_float(q6.y), g6, acc);
                acc = fmaf(__uint_as_float(q7.y), g7, acc);
            }
            for (; j < je; ++j) {
                uint2 p = sorted[j];
                acc = fmaf(__uint_as_float(p.y),
                           bf2f(support[((size_t)(p.x & 131071u) << 6) + lane]),
                           acc);
            }
            out[(size_t)r * OUT_F + lane] = acc;
        }
    } else {
        // oversize bucket (statistically unreachable): direct filter path
        #pragma unroll
        for (int q = 0; q < 4; ++q) {
            const int rr = wid * 4 + q;
            const int r  = row0 + rr;
            if (r >= N_NODES) break;
            float acc = bias[lane];
            for (int j = s; j < e; ++j) {
                uint2 p = binned[j];
                if ((int)(p.x >> 17) == rr)
                    acc = fmaf(__uint_as_float(p.y),
                               bf2f(support[((size_t)(p.x & 131071u) << 6) + lane]),
                               acc);
            }
            out[(size_t)r * OUT_F + lane] = acc;
        }
    }
}

// ===========================================================================
// Fallback path (ws too small): bias-init + atomic scatter (bf16 support)
// ===========================================================================
__global__ __launch_bounds__(256) void bias_init_kernel(
    float* __restrict__ out, const float* __restrict__ bias, int total4)
{
    const float4* b4 = (const float4*)bias;
    float4* o4 = (float4*)out;
    int i = blockIdx.x * blockDim.x + threadIdx.x;
    int stride = gridDim.x * blockDim.x;
    for (; i < total4; i += stride)
        o4[i] = b4[i & 15];
}

__global__ __launch_bounds__(256) void scatter_kernel(
    const float* __restrict__ vals, const int* __restrict__ rows,
    const int* __restrict__ cols, const unsigned short* __restrict__ support,
    float* __restrict__ out, int nE)
{
    const int e = blockIdx.x * 4 + (threadIdx.x >> 6);
    if (e >= nE) return;
    const int f = threadIdx.x & 63;
    const float m = vals[e] * bf2f(support[(size_t)cols[e] * OUT_F + f]);
    atomicAdd(&out[(size_t)rows[e] * OUT_F + f], m);
}

// ===========================================================================
extern "C" void kernel_launch(void* const* d_in, const int* in_sizes, int n_in,
                              void* d_out, int out_size, void* d_ws, size_t ws_size,
                              hipStream_t stream) {
    const float* input    = (const float*)d_in[0];
    const float* weights  = (const float*)d_in[1];
    const float* bias     = (const float*)d_in[2];
    const float* adj_vals = (const float*)d_in[3];
    const int*   adj_rows = (const int*)d_in[4];
    const int*   adj_cols = (const int*)d_in[5];
    const int nE = in_sizes[3];

    float* out = (float*)d_out;
    const int gemmBlocks = (N_NODES + 63) / 64;   // 1563

    // workspace layout (16B-aligned offsets)
    char* ws = (char*)d_ws;
    const size_t off_support = 0;                       // N*64 bf16 = 12.8 MB
    const size_t off_base    = 12800000;                // (NB+1) ints
    const size_t off_cursor  = off_base + 6400;         // NB ints
    const size_t off_binned  = off_cursor + 6400;       // nE uint2
    const size_t required    = off_binned + (size_t)nE * 8;

    unsigned short* support = (unsigned short*)(ws + off_support);
    int*   bbase   = (int*)  (ws + off_base);
    int*   cursor  = (int*)  (ws + off_cursor);
    uint2* binned  = (uint2*)(ws + off_binned);

    if (ws_size >= required) {
        // 1) cnt (cursor buffer) = 0
        hipLaunchKernelGGL(zero_kernel, dim3((NB + 255) / 256), dim3(256),
                           0, stream, cursor, NB);
        // 2) fused: support = bf16(input @ W)  ||  per-bucket counts
        hipLaunchKernelGGL(gemm_count_kernel, dim3(gemmBlocks + 256), dim3(256),
                           0, stream, input, weights, support,
                           adj_rows, cursor, nE, gemmBlocks);
        // 3) scan -> base, cursor
        hipLaunchKernelGGL(scan_kernel, dim3(1), dim3(256), 0, stream,
                           cursor, bbase, cursor, nE);
        // 4) bin edges by bucket (clustered writes)
        hipLaunchKernelGGL(bin_kernel, dim3((nE + BIN_TILE - 1) / BIN_TILE),
                           dim3(256), 0, stream,
                           adj_rows, adj_cols, adj_vals, cursor, binned, nE);
        // 5) fused per-bucket LDS row-sort + per-row wave gather + bias
        hipLaunchKernelGGL(csr_spmm, dim3(NB), dim3(1024), 0, stream,
                           bbase, binned, support, bias, out);
    } else {
        // minimal-workspace fallback
        hipLaunchKernelGGL(gemm_count_kernel, dim3(gemmBlocks), dim3(256),
                           0, stream, input, weights, support,
                           adj_rows, (int*)nullptr, nE, gemmBlocks);
        hipLaunchKernelGGL(bias_init_kernel, dim3(2048), dim3(256), 0, stream,
                           out, bias, N_NODES * OUT_F / 4);
        hipLaunchKernelGGL(scatter_kernel, dim3((nE + 3) / 4), dim3(256),
                           0, stream, adj_vals, adj_rows, adj_cols, support,
                           out, nE);
    }
}

// Round 11
// 130.533 us; speedup vs baseline: 5.6709x; 1.0286x over previous
//
#include <hip/hip_runtime.h>
#include <hip/hip_bf16.h>

#define N_NODES 100000
#define IN_F 128
#define OUT_F 64
#define BROWS 64                  // rows per bucket
#define NB 1563                   // ceil(100000/64)
#define BIN_TILE 4096             // edges per bin tile (16 per thread)
#define CSB_CAP 2048              // max edges per bucket in csr_spmm LDS
#define ASTRIDE 132               // 128 + 4 pad: 16B-aligned rows, b128-clean

// RNE float -> bf16 (bits)
__device__ __forceinline__ unsigned short f2bf(float x) {
    unsigned u = __float_as_uint(x);
    u += 0x7FFFu + ((u >> 16) & 1u);
    return (unsigned short)(u >> 16);
}
// bf16 (bits) -> float (exact)
__device__ __forceinline__ float bf2f(unsigned short s) {
    return __uint_as_float(((unsigned)s) << 16);
}

// ===========================================================================
// B1: per-bucket edge counts (LDS-aggregated histogram -> global add)
// ===========================================================================
__global__ __launch_bounds__(256) void count_kernel(
    const int* __restrict__ rows, int* __restrict__ cnt, int nE)
{
    __shared__ int hist[NB];
    const int t = threadIdx.x;
    for (int i = t; i < NB; i += 256) hist[i] = 0;
    __syncthreads();

    for (int e = blockIdx.x * 256 + t; e < nE; e += gridDim.x * 256)
        atomicAdd(&hist[rows[e] >> 6], 1);
    __syncthreads();

    for (int i = t; i < NB; i += 256) {
        int h = hist[i];
        if (h) atomicAdd(&cnt[i], h);
    }
}

// ===========================================================================
// B2: exclusive scan of NB counts (single block, 8 elems/thread).
// base <- scan(cnt), cursor <- same, base[NB] = nE.
// ===========================================================================
__global__ __launch_bounds__(256) void scan_kernel(
    const int* __restrict__ cnt, int* __restrict__ base,
    int* __restrict__ cursor, int nE)
{
    __shared__ int lds[256];
    const int t = threadIdx.x;
    const int i0 = t * 8;
    int c[8];
    int tot = 0;
    #pragma unroll
    for (int k = 0; k < 8; ++k) {
        c[k] = (i0 + k < NB) ? cnt[i0 + k] : 0;
        tot += c[k];
    }

    lds[t] = tot;
    __syncthreads();
    int sum = tot;
    #pragma unroll
    for (int off = 1; off < 256; off <<= 1) {
        int y = (t >= off) ? lds[t - off] : 0;
        __syncthreads();
        sum += y;
        lds[t] = sum;
        __syncthreads();
    }
    int run = sum - tot;

    #pragma unroll
    for (int k = 0; k < 8; ++k) {
        if (i0 + k < NB) { base[i0 + k] = run; cursor[i0 + k] = run; }
        run += c[k];
    }
    if (t == 0) base[NB] = nE;
}

// ===========================================================================
// Kernel fused: blocks [0, gemmBlocks) -> support = bf16(input @ W);
// blocks [gemmBlocks, +binBlocks) -> bin edges by bucket. The two are
// independent chains; fusing overlaps gemm compute with bin's memory work.
// LDS overlaid in one 33.8 KB buffer (gemm: A-tile [64][132] f32;
// bin: hist[NB]+lbase[NB]).
// gemm: lane = row; stage via ds_write_b128, read via ds_read_b128
// (stride 132 floats -> every bank hit exactly 8x per wave: conflict-free).
// ===========================================================================
__global__ __launch_bounds__(256) void gemm_bin_kernel(
    const float* __restrict__ in, const float* __restrict__ W,
    unsigned short* __restrict__ support,
    const int* __restrict__ rows, const int* __restrict__ cols,
    const float* __restrict__ vals, int* __restrict__ cursor,
    uint2* __restrict__ binned, int nE, int gemmBlocks)
{
    __shared__ __align__(16) char smem[64 * ASTRIDE * 4];   // 33792 B
    const int t = threadIdx.x;

    if ((int)blockIdx.x >= gemmBlocks) {
        // ---------------- bin body ----------------
        int* hist  = (int*)smem;          // NB ints
        int* lbase = hist + NB;           // NB ints (12.5 KB total, fits)
        const int tb = (blockIdx.x - gemmBlocks) * BIN_TILE;

        for (int i = t; i < NB; i += 256) hist[i] = 0;
        __syncthreads();

        int myr[16], myrank[16];
        #pragma unroll
        for (int i = 0; i < 16; ++i) {
            int e = tb + i * 256 + t;
            if (e < nE) {
                int r = rows[e];
                myr[i] = r;
                myrank[i] = atomicAdd(&hist[r >> 6], 1);
            } else myr[i] = -1;
        }
        __syncthreads();

        for (int i = t; i < NB; i += 256) {
            int h = hist[i];
            lbase[i] = h ? atomicAdd(&cursor[i], h) : 0;
        }
        __syncthreads();

        #pragma unroll
        for (int i = 0; i < 16; ++i) {
            int e = tb + i * 256 + t;
            if (e < nE) {
                int r = myr[i];
                unsigned pack = ((unsigned)(r & (BROWS - 1)) << 17)
                              | (unsigned)cols[e];
                binned[lbase[r >> 6] + myrank[i]] =
                    make_uint2(pack, __float_as_uint(vals[e]));
            }
        }
        return;
    }

    // ---------------- gemm body ----------------
    float* Alds = (float*)smem;
    const long row0 = (long)blockIdx.x * 64;

    // stage 64 rows x 128 floats as 2048 float4 ds_write_b128 (conflict-free)
    #pragma unroll
    for (int i = 0; i < 8; ++i) {
        int fi = t + i * 256;
        int r  = fi >> 5;                 // 32 float4 per row
        int c4 = (fi & 31) << 2;
        float4 v = make_float4(0.f, 0.f, 0.f, 0.f);
        if (row0 + r < N_NODES)
            v = *(const float4*)(in + (row0 + r) * IN_F + c4);
        *(float4*)(Alds + r * ASTRIDE + c4) = v;
    }
    __syncthreads();

    const int lane = t & 63;
    const int c0   = __builtin_amdgcn_readfirstlane((t >> 6) << 4);
    const float* __restrict__ Wp = W + c0;

    float acc[16];
    #pragma unroll
    for (int i = 0; i < 16; ++i) acc[i] = 0.f;

    const float* Ar = Alds + lane * ASTRIDE;
    #pragma unroll 4
    for (int k4 = 0; k4 < IN_F; k4 += 4) {
        const float4 av = *(const float4*)(Ar + k4);   // ds_read_b128
        #pragma unroll
        for (int j = 0; j < 4; ++j) {
            const float a = (j == 0) ? av.x : (j == 1) ? av.y
                           : (j == 2) ? av.z : av.w;
            const int k = k4 + j;
            const float4 w0 = *(const float4*)(Wp + k * OUT_F + 0);
            const float4 w1 = *(const float4*)(Wp + k * OUT_F + 4);
            const float4 w2 = *(const float4*)(Wp + k * OUT_F + 8);
            const float4 w3 = *(const float4*)(Wp + k * OUT_F + 12);
            acc[0]  = fmaf(a, w0.x, acc[0]);  acc[1]  = fmaf(a, w0.y, acc[1]);
            acc[2]  = fmaf(a, w0.z, acc[2]);  acc[3]  = fmaf(a, w0.w, acc[3]);
            acc[4]  = fmaf(a, w1.x, acc[4]);  acc[5]  = fmaf(a, w1.y, acc[5]);
            acc[6]  = fmaf(a, w1.z, acc[6]);  acc[7]  = fmaf(a, w1.w, acc[7]);
            acc[8]  = fmaf(a, w2.x, acc[8]);  acc[9]  = fmaf(a, w2.y, acc[9]);
            acc[10] = fmaf(a, w2.z, acc[10]); acc[11] = fmaf(a, w2.w, acc[11]);
            acc[12] = fmaf(a, w3.x, acc[12]); acc[13] = fmaf(a, w3.y, acc[13]);
            acc[14] = fmaf(a, w3.z, acc[14]); acc[15] = fmaf(a, w3.w, acc[15]);
        }
    }

    const long orow = row0 + lane;
    if (orow < N_NODES) {
        unsigned up[8];
        #pragma unroll
        for (int i = 0; i < 8; ++i)
            up[i] = (unsigned)f2bf(acc[2 * i]) |
                    ((unsigned)f2bf(acc[2 * i + 1]) << 16);
        unsigned short* o = support + orow * OUT_F + c0;   // 32B-aligned
        *(uint4*)(o + 0) = make_uint4(up[0], up[1], up[2], up[3]);
        *(uint4*)(o + 8) = make_uint4(up[4], up[5], up[6], up[7]);
    }
}

// ===========================================================================
// B4 (fused csr+spmm): one block (1024 thr = 16 waves) per bucket.
// Stage bucket's edges in LDS, row-sort in LDS, then 16 waves x 4 rows:
// per-row gather from bf16 support (8 gathers in flight), bias fused.
// ===========================================================================
__global__ __launch_bounds__(1024, 2) void csr_spmm(
    const int* __restrict__ base, const uint2* __restrict__ binned,
    const unsigned short* __restrict__ support, const float* __restrict__ bias,
    float* __restrict__ out)
{
    __shared__ uint2 stage[CSB_CAP];     // 16 KB
    __shared__ uint2 sorted[CSB_CAP];    // 16 KB
    __shared__ int rh[BROWS], rs[BROWS + 1], rc[BROWS];
    const int t = threadIdx.x;
    const int b = blockIdx.x;
    const int s = base[b], e = base[b + 1];
    const int n = e - s;
    const int wid  = t >> 6;      // 0..15
    const int lane = t & 63;
    const int row0 = b * BROWS;

    if (t < BROWS) rh[t] = 0;
    __syncthreads();

    if (n <= CSB_CAP) {
        for (int i = t; i < n; i += 1024) {
            uint2 p = binned[s + i];
            stage[i] = p;
            atomicAdd(&rh[p.x >> 17], 1);
        }
        __syncthreads();
        if (t < BROWS) {
            int v = rh[t];
            int inc = v;
            #pragma unroll
            for (int off = 1; off < BROWS; off <<= 1) {
                int y = __shfl_up(inc, off, 64);
                if (t >= off) inc += y;
            }
            rs[t] = inc - v;
            rc[t] = inc - v;
            if (t == BROWS - 1) rs[BROWS] = inc;
        }
        __syncthreads();
        for (int i = t; i < n; i += 1024) {
            uint2 p = stage[i];
            int pos = atomicAdd(&rc[p.x >> 17], 1);
            sorted[pos] = p;
        }
        __syncthreads();

        #pragma unroll
        for (int q = 0; q < 4; ++q) {
            const int rr = wid * 4 + q;
            const int r  = row0 + rr;
            if (r >= N_NODES) break;
            float acc = bias[lane];
            int j  = rs[rr];
            const int je = rs[rr + 1];
            for (; j + 7 < je; j += 8) {
                uint2 q0 = sorted[j + 0];
                uint2 q1 = sorted[j + 1];
                uint2 q2 = sorted[j + 2];
                uint2 q3 = sorted[j + 3];
                uint2 q4 = sorted[j + 4];
                uint2 q5 = sorted[j + 5];
                uint2 q6 = sorted[j + 6];
                uint2 q7 = sorted[j + 7];
                float g0 = bf2f(support[((size_t)(q0.x & 131071u) << 6) + lane]);
                float g1 = bf2f(support[((size_t)(q1.x & 131071u) << 6) + lane]);
                float g2 = bf2f(support[((size_t)(q2.x & 131071u) << 6) + lane]);
                float g3 = bf2f(support[((size_t)(q3.x & 131071u) << 6) + lane]);
                float g4 = bf2f(support[((size_t)(q4.x & 131071u) << 6) + lane]);
                float g5 = bf2f(support[((size_t)(q5.x & 131071u) << 6) + lane]);
                float g6 = bf2f(support[((size_t)(q6.x & 131071u) << 6) + lane]);
                float g7 = bf2f(support[((size_t)(q7.x & 131071u) << 6) + lane]);
                acc = fmaf(__uint_as_float(q0.y), g0, acc);
                acc = fmaf(__uint_as_float(q1.y), g1, acc);
                acc = fmaf(__uint_as_float(q2.y), g2, acc);
                acc = fmaf(__uint_as_float(q3.y), g3, acc);
                acc = fmaf(__uint_as_float(q4.y), g4, acc);
                acc = fmaf(__uint_as_float(q5.y), g5, acc);
                acc = fmaf(__uint_as_float(q6.y), g6, acc);
                acc = fmaf(__uint_as_float(q7.y), g7, acc);
            }
            for (; j < je; ++j) {
                uint2 p = sorted[j];
                acc = fmaf(__uint_as_float(p.y),
                           bf2f(support[((size_t)(p.x & 131071u) << 6) + lane]),
                           acc);
            }
            out[(size_t)r * OUT_F + lane] = acc;
        }
    } else {
        #pragma unroll
        for (int q = 0; q < 4; ++q) {
            const int rr = wid * 4 + q;
            const int r  = row0 + rr;
            if (r >= N_NODES) break;
            float acc = bias[lane];
            for (int j = s; j < e; ++j) {
                uint2 p = binned[j];
                if ((int)(p.x >> 17) == rr)
                    acc = fmaf(__uint_as_float(p.y),
                               bf2f(support[((size_t)(p.x & 131071u) << 6) + lane]),
                               acc);
            }
            out[(size_t)r * OUT_F + lane] = acc;
        }
    }
}

// ===========================================================================
// Fallback path (ws too small): bias-init + atomic scatter (bf16 support)
// ===========================================================================
__global__ __launch_bounds__(256) void bias_init_kernel(
    float* __restrict__ out, const float* __restrict__ bias, int total4)
{
    const float4* b4 = (const float4*)bias;
    float4* o4 = (float4*)out;
    int i = blockIdx.x * blockDim.x + threadIdx.x;
    int stride = gridDim.x * blockDim.x;
    for (; i < total4; i += stride)
        o4[i] = b4[i & 15];
}

__global__ __launch_bounds__(256) void scatter_kernel(
    const float* __restrict__ vals, const int* __restrict__ rows,
    const int* __restrict__ cols, const unsigned short* __restrict__ support,
    float* __restrict__ out, int nE)
{
    const int e = blockIdx.x * 4 + (threadIdx.x >> 6);
    if (e >= nE) return;
    const int f = threadIdx.x & 63;
    const float m = vals[e] * bf2f(support[(size_t)cols[e] * OUT_F + f]);
    atomicAdd(&out[(size_t)rows[e] * OUT_F + f], m);
}

// ===========================================================================
extern "C" void kernel_launch(void* const* d_in, const int* in_sizes, int n_in,
                              void* d_out, int out_size, void* d_ws, size_t ws_size,
                              hipStream_t stream) {
    const float* input    = (const float*)d_in[0];
    const float* weights  = (const float*)d_in[1];
    const float* bias     = (const float*)d_in[2];
    const float* adj_vals = (const float*)d_in[3];
    const int*   adj_rows = (const int*)d_in[4];
    const int*   adj_cols = (const int*)d_in[5];
    const int nE = in_sizes[3];

    float* out = (float*)d_out;
    const int gemmBlocks = (N_NODES + 63) / 64;            // 1563
    const int binBlocks  = (nE + BIN_TILE - 1) / BIN_TILE; // 391

    // workspace layout (16B-aligned offsets)
    char* ws = (char*)d_ws;
    const size_t off_support = 0;                       // N*64 bf16 = 12.8 MB
    const size_t off_base    = 12800000;                // (NB+1) ints
    const size_t off_cursor  = off_base + 6400;         // NB ints
    const size_t off_binned  = off_cursor + 6400;       // nE uint2
    const size_t required    = off_binned + (size_t)nE * 8;

    unsigned short* support = (unsigned short*)(ws + off_support);
    int*   bbase   = (int*)  (ws + off_base);
    int*   cursor  = (int*)  (ws + off_cursor);
    uint2* binned  = (uint2*)(ws + off_binned);

    if (ws_size >= required) {
        // 1) cursor (as counts) = 0
        hipMemsetAsync(cursor, 0, NB * sizeof(int), stream);
        // 2) per-bucket counts
        hipLaunchKernelGGL(count_kernel, dim3(256), dim3(256), 0, stream,
                           adj_rows, cursor, nE);
        // 3) scan -> base, cursor
        hipLaunchKernelGGL(scan_kernel, dim3(1), dim3(256), 0, stream,
                           cursor, bbase, cursor, nE);
        // 4) fused: support = bf16(input @ W)  ||  bin edges by bucket
        hipLaunchKernelGGL(gemm_bin_kernel, dim3(gemmBlocks + binBlocks),
                           dim3(256), 0, stream,
                           input, weights, support,
                           adj_rows, adj_cols, adj_vals, cursor, binned,
                           nE, gemmBlocks);
        // 5) fused per-bucket LDS row-sort + per-row wave gather + bias
        hipLaunchKernelGGL(csr_spmm, dim3(NB), dim3(1024), 0, stream,
                           bbase, binned, support, bias, out);
    } else {
        // minimal-workspace fallback (gemm only, then atomic scatter)
        hipLaunchKernelGGL(gemm_bin_kernel, dim3(gemmBlocks), dim3(256),
                           0, stream, input, weights, support,
                           adj_rows, adj_cols, adj_vals, (int*)nullptr,
                           (uint2*)nullptr, nE, gemmBlocks);
        hipLaunchKernelGGL(bias_init_kernel, dim3(2048), dim3(256), 0, stream,
                           out, bias, N_NODES * OUT_F / 4);
        hipLaunchKernelGGL(scatter_kernel, dim3((nE + 3) / 4), dim3(256),
                           0, stream, adj_vals, adj_rows, adj_cols, support,
                           out, nE);
    }
}